// Round 21
// baseline (4151.136 us; speedup 1.0000x reference)
//
#include <hip/hip_runtime.h>
#include <cmath>

// ---- problem constants ----
#define NB 16
#define CC 32          // channels per dictionary (A and B each)
#define HH 256
#define WW 256
#define DD 250         // 256 - 7 + 1
#define ALPHA 2.0f     // 1 + 1/RHO
#define INVL 0.1f      // 1/L
#define THR 0.01f      // LAM/L

#define IMG_SZ (HH*WW)                       // 65536
#define IMG_TOT (NB*IMG_SZ)                  // 1,048,576
#define FLD_SZ (DD*DD)                       // 62,500
#define FLD_TOT ((size_t)NB*CC*FLD_SZ)       // 32,000,000

#define SRS 264                              // LDS row stride (floats)

// block-uniform float -> SGPR (filter taps become the s-operand of v_fma)
__device__ __forceinline__ float rfl(float x) {
    return __int_as_float(__builtin_amdgcn_readfirstlane(__float_as_int(x)));
}
__device__ __forceinline__ float sthr(float v) {
    float a = fabsf(v) - THR; a = a > 0.f ? a : 0.f;
    return (v > 0.f) ? a : ((v < 0.f) ? -a : 0.f);
}

// conv: out[e][j] += wt[a][b] * res[row][q4 + b + j]
#define CONV_ROW(ACC, Aa) do { \
    _Pragma("unroll") \
    for (int b = 0; b < 7; ++b) { \
        const float wv = wt[Aa][b]; \
        ACC.x += wv*win[b+0]; ACC.y += wv*win[b+1]; \
        ACC.z += wv*win[b+2]; ACC.w += wv*win[b+3]; \
    } } while (0)

// gather (convT): img[d][j] += wt[a][b] * s[k][w4 + j - b]; stile idx = 8+j-b
#define GATH_ROW(ACC, Aa) do { \
    _Pragma("unroll") \
    for (int b = 0; b < 7; ++b) { \
        const float wv = wt[Aa][b]; \
        ACC.x += wv*win[8-b+0]; ACC.y += wv*win[8-b+1]; \
        ACC.z += wv*win[8-b+2]; ACC.w += wv*win[8-b+3]; \
    } } while (0)

// ---------------------------------------------------------------------------
// k_step v18: v17's fused step with CHANNEL-HALF grid split.
// grid = (16 ptiles, 2*nhalf roles, NB): f = role/nhalf, half = role%nhalf,
// channels [half*nch, half*nch+nch). Single-buffer stile (40448 B LDS),
// VGPR capped 64 -> with nhalf=2: 1024 blocks = 4 blocks/CU resident.
// Each (field,half) writes its own partial image (summed in k_res/k_final).
// ---------------------------------------------------------------------------
__global__ __launch_bounds__(512, 4) void k_step(
    const float* __restrict__ rin,          // res image (or y at step 0)
    const float* sx_cur, const float* su_cur,
    float* sx_on, float* su_on,             // s_old == s_next (read then write)
    float* __restrict__ Xp0, float* __restrict__ Xp1,
    float* __restrict__ Up0, float* __restrict__ Up1,
    const float* __restrict__ Afil, const float* __restrict__ Bfil,
    float cmom, int first, int nhalf, int nch)
{
    __shared__ __align__(16) float resT[22*SRS];
    __shared__ __align__(16) float stile[16*SRS];

    const int p0   = blockIdx.x * 16;
    const int role = blockIdx.y;
    const int f    = role / nhalf;
    const int half = role - f*nhalf;
    const int ch0  = half * nch;
    const int n    = blockIdx.z;
    const int tid  = threadIdx.x;
    const bool isx = (f == 0);

    // zero the s-tile buffer once (borders + beyond-DD rows rely on this)
    {
        float4 z = make_float4(0.f,0.f,0.f,0.f);
        float4* sp = (float4*)&stile[0];
        for (int i = tid; i < 16*SRS/4; i += 512) sp[i] = z;
    }
    // stage res tile rows [p0 .. p0+21], cols 0..255 (+8 zero cols pad)
    {
        const float* rb = rin + (size_t)n * IMG_SZ;
        for (int i = tid; i < 22*66; i += 512) {
            int r  = i / 66;
            int c4 = (i - r*66) << 2;
            int gr = p0 + r;
            float4 v = make_float4(0.f,0.f,0.f,0.f);
            if (gr < HH && c4 < WW) v = *(const float4*)(rb + gr*WW + c4);
            *(float4*)&resT[r*SRS + c4] = v;
        }
    }
    __syncthreads();

    const int rg  = tid >> 6;               // 0..7 (wave-uniform)
    const int q4  = (tid & 63) << 2;        // 0..252
    const bool qok = (q4 <= 248);
    const int p_0 = p0 + 2*rg;              // conv output rows p_0, p_0+1

    const float* Wb   = isx ? Afil : Bfil;
    const float* scur = isx ? sx_cur : su_cur;
    float*       sON  = isx ? sx_on  : su_on;
    float*       img  = (isx ? (half ? Xp1 : Xp0) : (half ? Up1 : Up0))
                        + (size_t)n * IMG_SZ;

    const bool momentum = (!first) && (cmom != 0.f);
    const bool plain    = (!first) && (cmom == 0.f);

    float4 ia0 = make_float4(0.f,0.f,0.f,0.f), ia1 = ia0, ia2 = ia0;

    const size_t fbase = (size_t)n * CC * FLD_SZ;
    const bool r0ok = qok && (p_0     < DD);
    const bool r1ok = qok && (p_0 + 1 < DD);
    const size_t off0 = fbase + (size_t)p_0*DD + q4;       // + c*FLD_SZ
    const size_t off1 = off0 + DD;

    for (int ci = 0; ci < nch; ++ci) {
        const int c = ch0 + ci;
        // filter taps -> SGPRs
        float wt[7][7];
        {
            const float* Wp = Wb + c*49;
#pragma unroll
            for (int a = 0; a < 7; ++a)
#pragma unroll
                for (int b = 0; b < 7; ++b)
                    wt[a][b] = rfl(Wp[a*7 + b]);
        }

        const size_t co = (size_t)c * FLD_SZ;
        float4 sc0 = make_float4(0.f,0.f,0.f,0.f), sc1 = sc0, so0 = sc0, so1 = sc0;
        if (momentum) {
            if (r0ok) { sc0 = *(const float4*)(scur + co + off0);
                        so0 = *(const float4*)(sON  + co + off0); }
            if (r1ok) { sc1 = *(const float4*)(scur + co + off1);
                        so1 = *(const float4*)(sON  + co + off1); }
        } else if (plain) {
            if (r0ok) sc0 = *(const float4*)(scur + co + off0);
            if (r1ok) sc1 = *(const float4*)(scur + co + off1);
        }

        // conv: rows p_0, p_0+1 from res rows (2rg .. 2rg+7)
        float4 a0 = make_float4(0.f,0.f,0.f,0.f), a1 = a0;
#pragma unroll
        for (int rr = 0; rr < 8; ++rr) {
            const float* lp = &resT[(2*rg + rr)*SRS + q4];
            float4 A0 = *(const float4*)lp;
            float4 A1 = *(const float4*)(lp + 4);
            float4 A2 = *(const float4*)(lp + 8);
            const float win[12] = {A0.x,A0.y,A0.z,A0.w, A1.x,A1.y,A1.z,A1.w,
                                   A2.x,A2.y,A2.z,A2.w};
            if (rr <= 6) CONV_ROW(a0, rr);
            if (rr >= 1) CONV_ROW(a1, rr-1);
        }

        // epilogue: s_next values
        float4 o0 = make_float4(a0.x*INVL, a0.y*INVL, a0.z*INVL, a0.w*INVL);
        float4 o1 = make_float4(a1.x*INVL, a1.y*INVL, a1.z*INVL, a1.w*INVL);
        if (momentum) {
            o0.x += sc0.x + cmom*(sc0.x - so0.x);
            o0.y += sc0.y + cmom*(sc0.y - so0.y);
            o0.z += sc0.z + cmom*(sc0.z - so0.z);
            o0.w += sc0.w + cmom*(sc0.w - so0.w);
            o1.x += sc1.x + cmom*(sc1.x - so1.x);
            o1.y += sc1.y + cmom*(sc1.y - so1.y);
            o1.z += sc1.z + cmom*(sc1.z - so1.z);
            o1.w += sc1.w + cmom*(sc1.w - so1.w);
        } else if (plain) {
            o0.x += sc0.x; o0.y += sc0.y; o0.z += sc0.z; o0.w += sc0.w;
            o1.x += sc1.x; o1.y += sc1.y; o1.z += sc1.z; o1.w += sc1.w;
        }
        if (!isx) {
            o0.x = sthr(o0.x); o0.y = sthr(o0.y); o0.z = sthr(o0.z); o0.w = sthr(o0.w);
            o1.x = sthr(o1.x); o1.y = sthr(o1.y); o1.z = sthr(o1.z); o1.w = sthr(o1.w);
        }

        // global store of s_next (no LDS hazard; before the barriers)
        if (r0ok) {
            float* dst = sON + co + off0;
            if (q4 <= 244) *(float4*)dst = o0;
            else           *(float2*)dst = make_float2(o0.x, o0.y);
        }
        if (r1ok) {
            float* dst = sON + co + off1;
            if (q4 <= 244) *(float4*)dst = o1;
            else           *(float2*)dst = make_float2(o1.x, o1.y);
        }

        __syncthreads();                     // gather(prev ch) on stile done

        if (r0ok) {
            float* d0 = &stile[(2*rg)*SRS + q4 + 8];
            if (q4 <= 244) *(float4*)d0 = o0;
            else           *(float2*)d0 = make_float2(o0.x, o0.y);
        }
        if (r1ok) {
            float* d1 = &stile[(2*rg + 1)*SRS + q4 + 8];
            if (q4 <= 244) *(float4*)d1 = o1;
            else           *(float2*)d1 = make_float2(o1.x, o1.y);
        }
        __syncthreads();                     // stile writes visible

        // gather: img rows 3rg..3rg+2 <- convT(stile)
#pragma unroll
        for (int k9 = 0; k9 < 9; ++k9) {
            const int k = 3*rg - 6 + k9;
            if (k >= 0 && k < 16) {
                const float* sp = &stile[k*SRS + q4];
                float4 B0 = *(const float4*)sp;
                float4 B1 = *(const float4*)(sp + 4);
                float4 B2 = *(const float4*)(sp + 8);
                const float win[12] = {B0.x,B0.y,B0.z,B0.w, B1.x,B1.y,B1.z,B1.w,
                                       B2.x,B2.y,B2.z,B2.w};
                if (k9 <= 6)            GATH_ROW(ia0, 6 - k9);
                if (k9 >= 1 && k9 <= 7) GATH_ROW(ia1, 7 - k9);
                if (k9 >= 2)            GATH_ROW(ia2, 8 - k9);
            }
        }
    }

    // image write-out: rows h in [6,15] exclusive -> plain store;
    // boundary rows -> atomicAdd (buffers pre-zeroed by k_res / k_zero)
#pragma unroll
    for (int d = 0; d < 3; ++d) {
        const int h = 3*rg + d;
        if (h < 22) {
            const int habs = p0 + h;
            if (habs < HH) {
                float4 v = (d == 0) ? ia0 : (d == 1) ? ia1 : ia2;
                float* ip = img + (size_t)habs*WW + q4;
                if (h >= 6 && h <= 15) {
                    *(float4*)ip = v;
                } else {
                    atomicAdd(ip + 0, v.x);
                    atomicAdd(ip + 1, v.y);
                    atomicAdd(ip + 2, v.z);
                    atomicAdd(ip + 3, v.w);
                }
            }
        }
    }
}

// ---------------------------------------------------------------------------
// k_res: X = Xp0(+Xp1), U = Up0(+Up1); res = y - ALPHA*((1+cm)X - cm*Xc)
// - ((1+cm)U - cm*Uc); Xc/Uc := X/U; zero partials. All L3-hot.
// ---------------------------------------------------------------------------
__global__ __launch_bounds__(256) void k_res(
    const float* __restrict__ y,
    float* Xp0, float* Xp1, float* Up0, float* Up1,
    float* Xc, float* Uc,
    float* __restrict__ resb, float cm, int nparts)
{
    int i = blockIdx.x*256 + threadIdx.x;
    if (i >= IMG_TOT/4) return;
    float4 z = make_float4(0.f,0.f,0.f,0.f);
    float4 xc = ((const float4*)Xp0)[i];  ((float4*)Xp0)[i] = z;
    float4 uc = ((const float4*)Up0)[i];  ((float4*)Up0)[i] = z;
    if (nparts == 2) {
        float4 t = ((const float4*)Xp1)[i];  ((float4*)Xp1)[i] = z;
        xc.x += t.x; xc.y += t.y; xc.z += t.z; xc.w += t.w;
        float4 s = ((const float4*)Up1)[i];  ((float4*)Up1)[i] = z;
        uc.x += s.x; uc.y += s.y; uc.z += s.z; uc.w += s.w;
    }
    float4 xo = z, uo = z;
    if (cm != 0.f) {
        xo = ((const float4*)Xc)[i];
        uo = ((const float4*)Uc)[i];
    }
    ((float4*)Xc)[i] = xc;
    ((float4*)Uc)[i] = uc;
    float4 yv = ((const float4*)y)[i];
    const float cp = 1.f + cm;
    float4 r;
    r.x = yv.x - ALPHA*(cp*xc.x - cm*xo.x) - (cp*uc.x - cm*uo.x);
    r.y = yv.y - ALPHA*(cp*xc.y - cm*xo.y) - (cp*uc.y - cm*uo.y);
    r.z = yv.z - ALPHA*(cp*xc.z - cm*xo.z) - (cp*uc.z - cm*uo.z);
    r.w = yv.w - ALPHA*(cp*xc.w - cm*xo.w) - (cp*uc.w - cm*uo.w);
    ((float4*)resb)[i] = r;
}

__global__ __launch_bounds__(256) void k_zero4(float* a, float* b, float* c, float* d)
{
    int i = blockIdx.x*256 + threadIdx.x;
    if (i < IMG_TOT/4) {
        float4 z = make_float4(0.f,0.f,0.f,0.f);
        ((float4*)a)[i] = z;
        ((float4*)b)[i] = z;
        ((float4*)c)[i] = z;
        ((float4*)d)[i] = z;
    }
}

// k_final: Ax_hat = Xp0(+Xp1) -> axh; Bu_hat = Up0(+Up1) -> buh; yhat = sum.
// axh aliases Xp0, buh aliases Up0 (same-index read-then-write, safe).
__global__ __launch_bounds__(256) void k_final(
    float* axh, const float* __restrict__ Xp1,
    float* buh, const float* __restrict__ Up1,
    float* __restrict__ yhat, int nparts)
{
    int i = blockIdx.x*256 + threadIdx.x;
    if (i >= IMG_TOT/4) return;
    float4 x = ((const float4*)axh)[i];
    float4 u = ((const float4*)buh)[i];
    if (nparts == 2) {
        float4 t = ((const float4*)Xp1)[i];
        x.x += t.x; x.y += t.y; x.z += t.z; x.w += t.w;
        float4 s = ((const float4*)Up1)[i];
        u.x += s.x; u.y += s.y; u.z += s.z; u.w += s.w;
    }
    ((float4*)axh)[i] = x;
    ((float4*)buh)[i] = u;
    float4 s2 = make_float4(x.x+u.x, x.y+u.y, x.z+u.z, x.w+u.w);
    ((float4*)yhat)[i] = s2;
}

extern "C" void kernel_launch(void* const* d_in, const int* in_sizes, int n_in,
                              void* d_out, int out_size, void* d_ws, size_t ws_size,
                              hipStream_t stream) {
    const float* y = (const float*)d_in[0];
    const float* A = (const float*)d_in[1];
    const float* B = (const float*)d_in[2];

    float* out  = (float*)d_out;
    float* yhat = out;                          // [IMG_TOT]
    float* xout = out + IMG_TOT;                // [FLD_TOT]  s_15 x
    float* uout = xout + FLD_TOT;               // [FLD_TOT]  s_15 u
    float* axh  = uout + FLD_TOT;               // [IMG_TOT]  X partial 0 / Ax_hat
    float* buh  = axh + IMG_TOT;                // [IMG_TOT]  U partial 0 / Bu_hat

    float* ws   = (float*)d_ws;
    float* Px0  = ws;                           // [FLD_TOT]
    float* Pu0  = Px0 + FLD_TOT;                // [FLD_TOT]
    float* Xc   = Pu0 + FLD_TOT;                // [IMG_TOT]  combined X (prev gen)
    float* Uc   = Xc + IMG_TOT;                 // [IMG_TOT]  combined U (prev gen)
    float* Xp1  = Uc + IMG_TOT;                 // [IMG_TOT]  X partial 1 (if room)
    float* Up1  = Xp1 + IMG_TOT;                // [IMG_TOT]  U partial 1 (if room)

    // channel-half split only if ws holds the 2 extra partial images
    size_t need2 = (2*FLD_TOT + 4*(size_t)IMG_TOT) * sizeof(float); // ~272.8 MB
    const int nhalf = (ws_size >= need2) ? 2 : 1;
    const int nch   = CC / nhalf;
    if (nhalf == 1) { Xp1 = axh; Up1 = buh; }   // unused; keep pointers valid

    float* Px[2] = {Px0, xout};
    float* Pu[2] = {Pu0, uout};
    float* res   = yhat;                        // borrowed; rewritten by k_final

    // FISTA momentum coefficients; step t (>=1) uses cv[t-1]; cv[0]==0.
    float cv[15];
    {
        float t = 1.0f;
        for (int k = 0; k < 15; ++k) {
            float tn = (1.0f + sqrtf(1.0f + 4.0f*t*t)) * 0.5f;
            cv[k] = (t - 1.0f) / tn;
            t = tn;
        }
    }

    dim3 blk512(512), blk256(256);
    dim3 gS(16, 2*nhalf, NB);                   // (p-tile, field*half, n)
    int  gE = (IMG_TOT/4 + 255)/256;

    k_zero4<<<gE, blk256, 0, stream>>>(axh, buh, Xp1, Up1);

    // t = 0: res == y, no state reads; writes s_1 + accumulates gen-1 images
    k_step<<<gS, blk512, 0, stream>>>(y, Px[0], Pu[0], Px[1], Pu[1],
                                      axh, Xp1, buh, Up1, A, B, 0.0f, 1,
                                      nhalf, nch);

    for (int t = 1; t < 15; ++t) {
        float cm = cv[t-1];
        k_res<<<gE, blk256, 0, stream>>>(y, axh, Xp1, buh, Up1, Xc, Uc,
                                         res, cm, nhalf);
        k_step<<<gS, blk512, 0, stream>>>(res, Px[t&1], Pu[t&1],
                                          Px[(t+1)&1], Pu[(t+1)&1],
                                          axh, Xp1, buh, Up1, A, B, cm, 0,
                                          nhalf, nch);
    }

    k_final<<<gE, blk256, 0, stream>>>(axh, Xp1, buh, Up1, yhat, nhalf);
}

// Round 22
// 3796.964 us; speedup vs baseline: 1.0933x; 1.0933x over previous
//
#include <hip/hip_runtime.h>
#include <cmath>

// ---- problem constants ----
#define NB 16
#define CC 32          // channels per dictionary (A and B each)
#define HH 256
#define WW 256
#define DD 250         // 256 - 7 + 1
#define ALPHA 2.0f     // 1 + 1/RHO
#define INVL 0.1f      // 1/L
#define THR 0.01f      // LAM/L

#define IMG_SZ (HH*WW)                       // 65536
#define IMG_TOT (NB*IMG_SZ)                  // 1,048,576
#define FLD_SZ (DD*DD)                       // 62,500
#define FLD_TOT ((size_t)NB*CC*FLD_SZ)       // 32,000,000

#define SRS 264                              // LDS row stride (floats)

// block-uniform float -> SGPR (filter taps become the s-operand of v_fma)
__device__ __forceinline__ float rfl(float x) {
    return __int_as_float(__builtin_amdgcn_readfirstlane(__float_as_int(x)));
}
__device__ __forceinline__ float sthr(float v) {
    float a = fabsf(v) - THR; a = a > 0.f ? a : 0.f;
    return (v > 0.f) ? a : ((v < 0.f) ? -a : 0.f);
}

// conv: out[e][j] += wt[a][b] * res[row][q4 + b + j]
#define CONV_ROW(ACC, Aa) do { \
    _Pragma("unroll") \
    for (int b = 0; b < 7; ++b) { \
        const float wv = wt[Aa][b]; \
        ACC.x += wv*win[b+0]; ACC.y += wv*win[b+1]; \
        ACC.z += wv*win[b+2]; ACC.w += wv*win[b+3]; \
    } } while (0)

// gather (convT): img[d][j] += wt[a][b] * s[k][w4 + j - b]; stile idx = 8+j-b
#define GATH_ROW(ACC, Aa) do { \
    _Pragma("unroll") \
    for (int b = 0; b < 7; ++b) { \
        const float wv = wt[Aa][b]; \
        ACC.x += wv*win[8-b+0]; ACC.y += wv*win[8-b+1]; \
        ACC.z += wv*win[8-b+2]; ACC.w += wv*win[8-b+3]; \
    } } while (0)

// ---------------------------------------------------------------------------
// k_step v19: v17 (proven 3.82 ms; single-buffer stile, VGPR<=64) +
// s_setprio(1) around the two FMA clusters (conv, gather). With 2
// independent blocks per CU at different phases, a wave in its FMA burst
// wins issue arbitration over the other block's LDS/barrier waves (T5).
// ---------------------------------------------------------------------------
__global__ __launch_bounds__(512, 4) void k_step(
    const float* __restrict__ rin,          // res image (or y at step 0)
    const float* sx_cur, const float* su_cur,
    float* sx_on, float* su_on,             // s_old == s_next (read then write)
    float* __restrict__ Ximg, float* __restrict__ Uimg,
    const float* __restrict__ Afil, const float* __restrict__ Bfil,
    float cmom, int first)
{
    __shared__ __align__(16) float resT[22*SRS];
    __shared__ __align__(16) float stile[16*SRS];

    const int p0  = blockIdx.x * 16;
    const int f   = blockIdx.y;
    const int n   = blockIdx.z;
    const int tid = threadIdx.x;
    const bool isx = (f == 0);

    // zero the s-tile buffer once (borders + beyond-DD rows rely on this)
    {
        float4 z = make_float4(0.f,0.f,0.f,0.f);
        float4* sp = (float4*)&stile[0];
        for (int i = tid; i < 16*SRS/4; i += 512) sp[i] = z;
    }
    // stage res tile rows [p0 .. p0+21], cols 0..255 (+8 zero cols pad)
    {
        const float* rb = rin + (size_t)n * IMG_SZ;
        for (int i = tid; i < 22*66; i += 512) {
            int r  = i / 66;
            int c4 = (i - r*66) << 2;
            int gr = p0 + r;
            float4 v = make_float4(0.f,0.f,0.f,0.f);
            if (gr < HH && c4 < WW) v = *(const float4*)(rb + gr*WW + c4);
            *(float4*)&resT[r*SRS + c4] = v;
        }
    }
    __syncthreads();

    const int rg  = tid >> 6;               // 0..7 (wave-uniform)
    const int q4  = (tid & 63) << 2;        // 0..252
    const bool qok = (q4 <= 248);
    const int p_0 = p0 + 2*rg;              // conv output rows p_0, p_0+1

    const float* Wb   = isx ? Afil : Bfil;
    const float* scur = isx ? sx_cur : su_cur;
    float*       sON  = isx ? sx_on  : su_on;
    float*       img  = (isx ? Ximg : Uimg) + (size_t)n * IMG_SZ;

    const bool momentum = (!first) && (cmom != 0.f);
    const bool plain    = (!first) && (cmom == 0.f);

    float4 ia0 = make_float4(0.f,0.f,0.f,0.f), ia1 = ia0, ia2 = ia0;

    const size_t fbase = (size_t)n * CC * FLD_SZ;
    const bool r0ok = qok && (p_0     < DD);
    const bool r1ok = qok && (p_0 + 1 < DD);
    const size_t off0 = fbase + (size_t)p_0*DD + q4;       // + c*FLD_SZ
    const size_t off1 = off0 + DD;

    for (int c = 0; c < CC; ++c) {
        // filter taps -> SGPRs
        float wt[7][7];
        {
            const float* Wp = Wb + c*49;
#pragma unroll
            for (int a = 0; a < 7; ++a)
#pragma unroll
                for (int b = 0; b < 7; ++b)
                    wt[a][b] = rfl(Wp[a*7 + b]);
        }

        const size_t co = (size_t)c * FLD_SZ;
        float4 sc0 = make_float4(0.f,0.f,0.f,0.f), sc1 = sc0, so0 = sc0, so1 = sc0;
        if (momentum) {
            if (r0ok) { sc0 = *(const float4*)(scur + co + off0);
                        so0 = *(const float4*)(sON  + co + off0); }
            if (r1ok) { sc1 = *(const float4*)(scur + co + off1);
                        so1 = *(const float4*)(sON  + co + off1); }
        } else if (plain) {
            if (r0ok) sc0 = *(const float4*)(scur + co + off0);
            if (r1ok) sc1 = *(const float4*)(scur + co + off1);
        }

        // conv: rows p_0, p_0+1 from res rows (2rg .. 2rg+7)  [prio boost]
        float4 a0 = make_float4(0.f,0.f,0.f,0.f), a1 = a0;
        __builtin_amdgcn_s_setprio(1);
#pragma unroll
        for (int rr = 0; rr < 8; ++rr) {
            const float* lp = &resT[(2*rg + rr)*SRS + q4];
            float4 A0 = *(const float4*)lp;
            float4 A1 = *(const float4*)(lp + 4);
            float4 A2 = *(const float4*)(lp + 8);
            const float win[12] = {A0.x,A0.y,A0.z,A0.w, A1.x,A1.y,A1.z,A1.w,
                                   A2.x,A2.y,A2.z,A2.w};
            if (rr <= 6) CONV_ROW(a0, rr);
            if (rr >= 1) CONV_ROW(a1, rr-1);
        }
        __builtin_amdgcn_s_setprio(0);

        // epilogue: s_next values
        float4 o0 = make_float4(a0.x*INVL, a0.y*INVL, a0.z*INVL, a0.w*INVL);
        float4 o1 = make_float4(a1.x*INVL, a1.y*INVL, a1.z*INVL, a1.w*INVL);
        if (momentum) {
            o0.x += sc0.x + cmom*(sc0.x - so0.x);
            o0.y += sc0.y + cmom*(sc0.y - so0.y);
            o0.z += sc0.z + cmom*(sc0.z - so0.z);
            o0.w += sc0.w + cmom*(sc0.w - so0.w);
            o1.x += sc1.x + cmom*(sc1.x - so1.x);
            o1.y += sc1.y + cmom*(sc1.y - so1.y);
            o1.z += sc1.z + cmom*(sc1.z - so1.z);
            o1.w += sc1.w + cmom*(sc1.w - so1.w);
        } else if (plain) {
            o0.x += sc0.x; o0.y += sc0.y; o0.z += sc0.z; o0.w += sc0.w;
            o1.x += sc1.x; o1.y += sc1.y; o1.z += sc1.z; o1.w += sc1.w;
        }
        if (!isx) {
            o0.x = sthr(o0.x); o0.y = sthr(o0.y); o0.z = sthr(o0.z); o0.w = sthr(o0.w);
            o1.x = sthr(o1.x); o1.y = sthr(o1.y); o1.z = sthr(o1.z); o1.w = sthr(o1.w);
        }

        // global store of s_next (no LDS hazard; before the barriers)
        if (r0ok) {
            float* dst = sON + co + off0;
            if (q4 <= 244) *(float4*)dst = o0;
            else           *(float2*)dst = make_float2(o0.x, o0.y);
        }
        if (r1ok) {
            float* dst = sON + co + off1;
            if (q4 <= 244) *(float4*)dst = o1;
            else           *(float2*)dst = make_float2(o1.x, o1.y);
        }

        __syncthreads();                     // gather(c-1) on stile complete

        if (r0ok) {
            float* d0 = &stile[(2*rg)*SRS + q4 + 8];
            if (q4 <= 244) *(float4*)d0 = o0;
            else           *(float2*)d0 = make_float2(o0.x, o0.y);
        }
        if (r1ok) {
            float* d1 = &stile[(2*rg + 1)*SRS + q4 + 8];
            if (q4 <= 244) *(float4*)d1 = o1;
            else           *(float2*)d1 = make_float2(o1.x, o1.y);
        }
        __syncthreads();                     // stile writes visible

        // gather: img rows 3rg..3rg+2 <- convT(stile)  [prio boost]
        __builtin_amdgcn_s_setprio(1);
#pragma unroll
        for (int k9 = 0; k9 < 9; ++k9) {
            const int k = 3*rg - 6 + k9;
            if (k >= 0 && k < 16) {
                const float* sp = &stile[k*SRS + q4];
                float4 B0 = *(const float4*)sp;
                float4 B1 = *(const float4*)(sp + 4);
                float4 B2 = *(const float4*)(sp + 8);
                const float win[12] = {B0.x,B0.y,B0.z,B0.w, B1.x,B1.y,B1.z,B1.w,
                                       B2.x,B2.y,B2.z,B2.w};
                if (k9 <= 6)            GATH_ROW(ia0, 6 - k9);
                if (k9 >= 1 && k9 <= 7) GATH_ROW(ia1, 7 - k9);
                if (k9 >= 2)            GATH_ROW(ia2, 8 - k9);
            }
        }
        __builtin_amdgcn_s_setprio(0);
    }

    // image write-out: rows h in [6,15] exclusive -> plain store;
    // boundary rows -> atomicAdd (buffers pre-zeroed by k_res / k_zero)
#pragma unroll
    for (int d = 0; d < 3; ++d) {
        const int h = 3*rg + d;
        if (h < 22) {
            const int habs = p0 + h;
            if (habs < HH) {
                float4 v = (d == 0) ? ia0 : (d == 1) ? ia1 : ia2;
                float* ip = img + (size_t)habs*WW + q4;
                if (h >= 6 && h <= 15) {
                    *(float4*)ip = v;
                } else {
                    atomicAdd(ip + 0, v.x);
                    atomicAdd(ip + 1, v.y);
                    atomicAdd(ip + 2, v.z);
                    atomicAdd(ip + 3, v.w);
                }
            }
        }
    }
}

// ---------------------------------------------------------------------------
// k_res: res = y - ALPHA*((1+cm)X - cm*Xprev) - ((1+cm)U - cm*Uprev);
// save combined X,U for next gen; re-zero the accumulators. All L3-hot.
// ---------------------------------------------------------------------------
__global__ __launch_bounds__(256) void k_res(
    const float* __restrict__ y,
    float* Xp, float* Up,                   // accumulated images (read then zero)
    float* Xc, float* Uc,                   // prev combined (read if cm!=0, overwrite)
    float* __restrict__ resb, float cm)
{
    int i = blockIdx.x*256 + threadIdx.x;
    if (i >= IMG_TOT/4) return;
    float4 xc = ((const float4*)Xp)[i];
    float4 uc = ((const float4*)Up)[i];
    float4 xo = make_float4(0.f,0.f,0.f,0.f), uo = xo;
    if (cm != 0.f) {
        xo = ((const float4*)Xc)[i];
        uo = ((const float4*)Uc)[i];
    }
    ((float4*)Xc)[i] = xc;
    ((float4*)Uc)[i] = uc;
    float4 z = make_float4(0.f,0.f,0.f,0.f);
    ((float4*)Xp)[i] = z;
    ((float4*)Up)[i] = z;
    float4 yv = ((const float4*)y)[i];
    const float cp = 1.f + cm;
    float4 r;
    r.x = yv.x - ALPHA*(cp*xc.x - cm*xo.x) - (cp*uc.x - cm*uo.x);
    r.y = yv.y - ALPHA*(cp*xc.y - cm*xo.y) - (cp*uc.y - cm*uo.y);
    r.z = yv.z - ALPHA*(cp*xc.z - cm*xo.z) - (cp*uc.z - cm*uo.z);
    r.w = yv.w - ALPHA*(cp*xc.w - cm*xo.w) - (cp*uc.w - cm*uo.w);
    ((float4*)resb)[i] = r;
}

__global__ __launch_bounds__(256) void k_zero2(float* a, float* b)
{
    int i = blockIdx.x*256 + threadIdx.x;
    if (i < IMG_TOT/4) {
        float4 z = make_float4(0.f,0.f,0.f,0.f);
        ((float4*)a)[i] = z;
        ((float4*)b)[i] = z;
    }
}

// k_final: yhat = axh + buh (axh/buh already hold Ax_hat / Bu_hat)
__global__ __launch_bounds__(256) void k_final(
    const float* __restrict__ axh, const float* __restrict__ buh,
    float* __restrict__ yhat)
{
    int i = blockIdx.x*256 + threadIdx.x;
    if (i < IMG_TOT/4) {
        float4 x = ((const float4*)axh)[i];
        float4 u = ((const float4*)buh)[i];
        float4 s;
        s.x = x.x + u.x; s.y = x.y + u.y; s.z = x.z + u.z; s.w = x.w + u.w;
        ((float4*)yhat)[i] = s;
    }
}

extern "C" void kernel_launch(void* const* d_in, const int* in_sizes, int n_in,
                              void* d_out, int out_size, void* d_ws, size_t ws_size,
                              hipStream_t stream) {
    const float* y = (const float*)d_in[0];
    const float* A = (const float*)d_in[1];
    const float* B = (const float*)d_in[2];

    float* out  = (float*)d_out;
    float* yhat = out;                          // [IMG_TOT]
    float* xout = out + IMG_TOT;                // [FLD_TOT]  s_15 x
    float* uout = xout + FLD_TOT;               // [FLD_TOT]  s_15 u
    float* axh  = uout + FLD_TOT;               // [IMG_TOT]  X accumulator / Ax_hat
    float* buh  = axh + IMG_TOT;                // [IMG_TOT]  U accumulator / Bu_hat

    float* ws   = (float*)d_ws;                 // needs 2*FLD_TOT + 2*IMG_TOT (264 MB)
    float* Px0  = ws;                           // [FLD_TOT]
    float* Pu0  = Px0 + FLD_TOT;                // [FLD_TOT]
    float* Xc   = Pu0 + FLD_TOT;                // [IMG_TOT]  combined X (prev gen)
    float* Uc   = Xc + IMG_TOT;                 // [IMG_TOT]  combined U (prev gen)

    // State ping-pong. k_step(t) reads s_t from P[t&1], writes s_{t+1} into
    // P[(t+1)&1] (also holds s_{t-1} = momentum "old"; exact-offset
    // read-then-write per thread). t=14 writes into P[1] = d_out slots.
    float* Px[2] = {Px0, xout};
    float* Pu[2] = {Pu0, uout};
    float* res   = yhat;                        // borrowed; rewritten by k_final

    // FISTA momentum coefficients; step t (>=1) uses cv[t-1]; cv[0]==0.
    float cv[15];
    {
        float t = 1.0f;
        for (int k = 0; k < 15; ++k) {
            float tn = (1.0f + sqrtf(1.0f + 4.0f*t*t)) * 0.5f;
            cv[k] = (t - 1.0f) / tn;
            t = tn;
        }
    }

    dim3 blk512(512), blk256(256);
    dim3 gS(16, 2, NB);                         // (p-tile, field, n)
    int  gE = (IMG_TOT/4 + 255)/256;

    k_zero2<<<gE, blk256, 0, stream>>>(axh, buh);

    // t = 0: res == y, no state reads; writes s_1 + accumulates gen-1 images
    k_step<<<gS, blk512, 0, stream>>>(y, Px[0], Pu[0], Px[1], Pu[1],
                                      axh, buh, A, B, 0.0f, 1);

    for (int t = 1; t < 15; ++t) {
        float cm = cv[t-1];
        k_res<<<gE, blk256, 0, stream>>>(y, axh, buh, Xc, Uc, res, cm);
        k_step<<<gS, blk512, 0, stream>>>(res, Px[t&1], Pu[t&1],
                                          Px[(t+1)&1], Pu[(t+1)&1],
                                          axh, buh, A, B, cm, 0);
    }

    k_final<<<gE, blk256, 0, stream>>>(axh, buh, yhat);
}